// Round 8
// baseline (1370.299 us; speedup 1.0000x reference)
//
#include <hip/hip_runtime.h>

#define RANK   32
#define DIM    128
#define WBATCH 32            // rows per WAVE-private batch
#define WGROUPS (WBATCH / 8) // 4 global_load_lds ops per batch

// Round-8: wave-private tasks, ZERO barriers. Rounds 5/6/7 showed the
// block-level batch's barrier lockstep is the structural cost: round 7's
// pipeline at 4 blocks/CU (199.7us) lost to round 5's serial loop at 8
// blocks/CU (145.7us). Here each wave owns (32-row batch, dim-half) with a
// private 4KB LDS buffer and a private vmcnt drain; waves self-pace and the
// SIMD fills one wave's ~700cy gather drain with other waves' compute.
// Task pairing (2i,2i+1 share a batch, same block) makes the duplicate
// gather an L1/L2 hit. Ordering = round-4's proven discipline:
// lgkmcnt(0) before DMA re-issue, vmcnt(0)+sched_barrier before ds_reads.
// Registers: w2r(32)+state ~66 natural; amdgpu_waves_per_eu(7,7) pins the
// 72-VGPR budget so the allocator neither spills (round 6) nor
// shrink-and-spills (round 4). 7 blocks/CU x 16KB LDS = 112KB.
__global__ __launch_bounds__(256)
__attribute__((amdgpu_waves_per_eu(7, 7)))
void lowrank_emb_kernel(
    const int* __restrict__ idx,
    const float* __restrict__ W1,
    const float* __restrict__ W2,
    float* __restrict__ out,
    int n_rows)
{
  __shared__ float lbuf[4][WBATCH * RANK];  // 4 waves x 4KB, wave-private

  const int lane        = threadIdx.x & 63;
  const int waveInBlock = threadIdx.x >> 6;
  const int globalWave  = blockIdx.x * 4 + waveInBlock;
  const int totalWaves  = gridDim.x * 4;

  float* wbuf = lbuf[waveInBlock];

  const int nTasks   = ((n_rows + WBATCH - 1) / WBATCH) * 2;  // (batch, dhalf)
  const int lastIdx  = n_rows - 1;

  // Task t: batch = t>>1, dhalf = t&1. Waves 2i and 2i+1 (same block) share a
  // batch -> the second wave's DMA hits L1/L2.
  int t = globalWave;
  if (t >= nTasks) return;

  const int dhalf = t & 1;                 // constant across grid-stride (totalWaves even)
  const int dim   = dhalf * 64 + lane;     // this lane's output dim

  // Per-lane W2 column (32 VGPRs), pinned (round-1 lesson: blocks remat).
  float w2r[RANK];
#pragma unroll
  for (int k = 0; k < RANK; ++k) w2r[k] = W2[k * DIM + dim];
#pragma unroll
  for (int k = 0; k < RANK; ++k) asm("" : "+v"(w2r[k]));

  const int rsub  = lane >> 3;   // row within an 8-row gather group
  const int chunk = lane & 7;    // 16B chunk within a row
  const int il    = lane & 31;   // idx slot this lane carries

  // Prefetch idx for the first task.
  int ivCur;
  {
    const int r = (t >> 1) * WBATCH + il;
    ivCur = idx[r < n_rows ? r : lastIdx];
  }

  for (; t < nTasks; t += totalWaves) {
    const int rowBase = (t >> 1) * WBATCH;

    // (1) My previous batch's ds_reads must retire before DMA overwrites.
    asm volatile("s_waitcnt lgkmcnt(0)" ::: "memory");
    __builtin_amdgcn_sched_barrier(0);

    // (2) Issue this batch's gathers: 4 x 1KB DMA-to-LDS. Lane l fetches 16B
    // chunk (l&7) of group-row (l>>3); HW writes base+l*16 = row-major [8][32].
#pragma unroll
    for (int g = 0; g < WGROUPS; ++g) {
      const int e = __shfl(ivCur, g * 8 + rsub, 64);
      const float* src = W1 + (size_t)e * RANK + chunk * 4;
      __builtin_amdgcn_global_load_lds(
          (const __attribute__((address_space(1))) unsigned*)src,
          (__attribute__((address_space(3))) unsigned*)(wbuf + g * (8 * RANK)),
          16, 0, 0);
    }

    // (3) Prefetch next task's idx; its latency drains with the gathers.
    {
      const int tn = t + totalWaves;
      const int r  = (tn >> 1) * WBATCH + il;
      ivCur = idx[(tn < nTasks && r < n_rows) ? r : lastIdx];
    }

    // (4) Private drain: only MY 4 DMAs (+idx load); no barrier.
    asm volatile("s_waitcnt vmcnt(0)" ::: "memory");
    __builtin_amdgcn_sched_barrier(0);

    // (5) Compute 32 rows x my 64-dim half: per row, 8 broadcast
    // (same-address, conflict-free) ds_read_b128 + 32 FMAs + 256B store.
    if (rowBase + WBATCH <= n_rows) {
#pragma unroll 2
      for (int r = 0; r < WBATCH; ++r) {
        const float4* rowp = reinterpret_cast<const float4*>(wbuf + r * RANK);
        float a0 = 0.f, a1 = 0.f;
#pragma unroll
        for (int c = 0; c < 8; ++c) {
          const float4 f = rowp[c];
          a0 = fmaf(f.x, w2r[4 * c + 0], a0);
          a1 = fmaf(f.y, w2r[4 * c + 1], a1);
          a0 = fmaf(f.z, w2r[4 * c + 2], a0);
          a1 = fmaf(f.w, w2r[4 * c + 3], a1);
        }
        out[(size_t)(rowBase + r) * DIM + dim] = a0 + a1;
      }
    } else {
      for (int r = 0; r < WBATCH; ++r) {
        const int orow = rowBase + r;
        if (orow >= n_rows) break;
        const float4* rowp = reinterpret_cast<const float4*>(wbuf + r * RANK);
        float a0 = 0.f, a1 = 0.f;
#pragma unroll
        for (int c = 0; c < 8; ++c) {
          const float4 f = rowp[c];
          a0 = fmaf(f.x, w2r[4 * c + 0], a0);
          a1 = fmaf(f.y, w2r[4 * c + 1], a1);
          a0 = fmaf(f.z, w2r[4 * c + 2], a0);
          a1 = fmaf(f.w, w2r[4 * c + 3], a1);
        }
        out[(size_t)orow * DIM + dim] = a0 + a1;
      }
    }
  }
}

extern "C" void kernel_launch(void* const* d_in, const int* in_sizes, int n_in,
                              void* d_out, int out_size, void* d_ws, size_t ws_size,
                              hipStream_t stream) {
  const int*   idx = (const int*)d_in[0];   // [4096*200]
  const float* W1  = (const float*)d_in[1]; // [1e6, 32]
  const float* W2  = (const float*)d_in[2]; // [32, 128]
  float*       out = (float*)d_out;         // [4096*200, 128]
  const int n_rows = in_sizes[0];

  const int threads = 256;   // 4 waves/block
  const int blocks  = 1792;  // 7 blocks/CU resident (LDS 112KB, VGPR 72)
  hipLaunchKernelGGL(lowrank_emb_kernel, dim3(blocks), dim3(threads), 0, stream,
                     idx, W1, W2, out, n_rows);
}